// Round 2
// baseline (667.789 us; speedup 1.0000x reference)
//
#include <hip/hip_runtime.h>
#include <hip/hip_bf16.h>
#include <stdint.h>

// Problem constants (match reference)
#define NUM_STEPS  256
#define INPUT_SIZE 784
#define N_NEURONS  512
#define CHUNKS     196   // 784 / 4 elements per thread

// bf16 <-> fp32 helpers (bit-exact widen; RNE narrow)
__device__ __forceinline__ float bf2f(unsigned short u) {
    union { uint32_t i; float f; } v; v.i = ((uint32_t)u) << 16; return v.f;
}
__device__ __forceinline__ unsigned short f2bf(float f) {
    union { float f; uint32_t i; } v; v.f = f;
    uint32_t x = v.i;
    uint32_t r = (x + 0x7fffu + ((x >> 16) & 1u)) >> 16;
    return (unsigned short)r;
}

// One block per neuron row; the full 256-step scan runs in-block (rows are
// independent: row i only needs its own dot product I[i]=W[i,:]·x_t, its own
// scalar state, and the shared image / pre-trace, which we recompute locally).
// Threads 0..195 each own 4 consecutive weight-row elements in registers.
// Per step: vectorized img load -> per-thread partial -> wave shuffle-reduce ->
// 4-slot LDS (double-buffered, single __syncthreads) -> scalar LIF update
// (redundantly in every thread) -> STDP weight update + clamp -> store.
template <bool F32>
__device__ void scan_run(const void* __restrict__ img_v,
                         const void* __restrict__ W_v,
                         void* __restrict__ out_v)
{
    const int row  = blockIdx.x;
    const int tid  = threadIdx.x;
    const bool act = tid < CHUNKS;
    const int col4 = tid << 2;
    const int wave = tid >> 6;
    const int lane = tid & 63;

    __shared__ float red[2][4];

    const size_t WREC = (size_t)NUM_STEPS * N_NEURONS * INPUT_SIZE;
    const size_t SREC = (size_t)NUM_STEPS * N_NEURONS;

    // fp32 working copies: weight-row chunk + pre-trace chunk
    float w0 = 0.f, w1 = 0.f, w2 = 0.f, w3 = 0.f;
    float p0 = 0.f, p1 = 0.f, p2 = 0.f, p3 = 0.f;
    if (act) {
        if constexpr (F32) {
            const float* W0 = (const float*)W_v;
            const float4 wv = *(const float4*)(W0 + (size_t)row * INPUT_SIZE + col4);
            w0 = wv.x; w1 = wv.y; w2 = wv.z; w3 = wv.w;
        } else {
            const unsigned short* W0 = (const unsigned short*)W_v;
            const ushort4 wv = *(const ushort4*)(W0 + (size_t)row * INPUT_SIZE + col4);
            w0 = bf2f(wv.x); w1 = bf2f(wv.y); w2 = bf2f(wv.z); w3 = bf2f(wv.w);
        }
    }

    float syn = 0.f, mem = 0.f, spk_prev = 0.f, post = 0.f;

    for (int t = 0; t < NUM_STEPS; ++t) {
        float x0 = 0.f, x1 = 0.f, x2 = 0.f, x3 = 0.f;
        float partial = 0.f;
        if (act) {
            if constexpr (F32) {
                const float* img = (const float*)img_v;
                const float4 xv = *(const float4*)(img + (size_t)t * INPUT_SIZE + col4);
                x0 = xv.x; x1 = xv.y; x2 = xv.z; x3 = xv.w;
            } else {
                const unsigned short* img = (const unsigned short*)img_v;
                const ushort4 xv = *(const ushort4*)(img + (size_t)t * INPUT_SIZE + col4);
                x0 = bf2f(xv.x); x1 = bf2f(xv.y); x2 = bf2f(xv.z); x3 = bf2f(xv.w);
            }
            partial = w0 * x0 + w1 * x1 + w2 * x2 + w3 * x3;
        }
        // wave-level tree reduce (64 lanes)
        #pragma unroll
        for (int off = 32; off > 0; off >>= 1)
            partial += __shfl_down(partial, off, 64);
        if (lane == 0) red[t & 1][wave] = partial;
        __syncthreads();
        const float I = red[t & 1][0] + red[t & 1][1] + red[t & 1][2] + red[t & 1][3];

        // LIF scalar state (wave-uniform, computed in every thread)
        syn = 0.9f * syn + I;                       // ALPHA
        mem = 0.8f * mem + syn - spk_prev;          // BETA, subtract-reset (THRESHOLD=1)
        const float spk = (mem > 1.0f) ? 1.0f : 0.0f;
        post = 0.9f * post + spk;                   // BETA_MINUS
        const float ap = 0.008f  * spk;             // A_PLUS  * spk
        const float am = 0.0066f * post;            // A_MINUS * post

        const size_t r = (size_t)t * N_NEURONS + row;
        if (act) {
            // STDP update + clamp (pre-trace BEFORE its recurrence update)
            w0 = fminf(fmaxf(w0 + ap * p0 - am * x0, 0.f), 1.f);
            w1 = fminf(fmaxf(w1 + ap * p1 - am * x1, 0.f), 1.f);
            w2 = fminf(fmaxf(w2 + ap * p2 - am * x2, 0.f), 1.f);
            w3 = fminf(fmaxf(w3 + ap * p3 - am * x3, 0.f), 1.f);

            if constexpr (F32) {
                float* out = (float*)out_v;
                *(float4*)(out + r * INPUT_SIZE + col4) = make_float4(w0, w1, w2, w3);
            } else {
                unsigned short* out = (unsigned short*)out_v;
                ushort4 ov;
                ov.x = f2bf(w0); ov.y = f2bf(w1); ov.z = f2bf(w2); ov.w = f2bf(w3);
                *(ushort4*)(out + r * INPUT_SIZE + col4) = ov;
            }

            // pre-trace recurrence: pre = BETA_PLUS*pre + x_t
            p0 = 0.9f * p0 + x0;
            p1 = 0.9f * p1 + x1;
            p2 = 0.9f * p2 + x2;
            p3 = 0.9f * p3 + x3;
        }
        if (tid == 0) {
            if constexpr (F32) {
                float* out = (float*)out_v;
                out[WREC + 0 * SREC + r] = spk;
                out[WREC + 1 * SREC + r] = mem;
                out[WREC + 2 * SREC + r] = syn;
                out[WREC + 3 * SREC + r] = post;
            } else {
                unsigned short* out = (unsigned short*)out_v;
                out[WREC + 0 * SREC + r] = f2bf(spk);
                out[WREC + 1 * SREC + r] = f2bf(mem);
                out[WREC + 2 * SREC + r] = f2bf(syn);
                out[WREC + 3 * SREC + r] = f2bf(post);
            }
        }
        spk_prev = spk;
    }
}

__global__ __launch_bounds__(256) void snn_row_scan_kernel(
    const void* __restrict__ img,
    const void* __restrict__ W,
    void* __restrict__ out)
{
    // Runtime dtype sniff (wave-uniform): bf16 data in [0,1] never has a
    // 16-bit halfword > 0x3F80; fp32 data's low halfwords are random mantissa
    // bits (P(miss) ~ 0.25^64). All threads read the same 256 bytes -> the
    // branch is uniform, so the __syncthreads inside each path is safe.
    const unsigned short* w16 = (const unsigned short*)W;
    bool f32 = false;
    for (int i = 0; i < 128; ++i) f32 |= (w16[i] > 0x3F80u);
    if (f32) scan_run<true >(img, W, out);
    else     scan_run<false>(img, W, out);
}

extern "C" void kernel_launch(void* const* d_in, const int* in_sizes, int n_in,
                              void* d_out, int out_size, void* d_ws, size_t ws_size,
                              hipStream_t stream) {
    (void)in_sizes; (void)n_in; (void)d_ws; (void)ws_size; (void)out_size;
    snn_row_scan_kernel<<<dim3(N_NEURONS), dim3(256), 0, stream>>>(d_in[0], d_in[1], d_out);
}